// Round 12
// baseline (136.567 us; speedup 1.0000x reference)
//
#include <hip/hip_runtime.h>

typedef __attribute__((ext_vector_type(8))) short short8;
typedef __attribute__((ext_vector_type(16))) float f32x16;

// ws layout (K reordered: K = f*576 + j*64 + c  -> zero 8th feature slot GONE):
//   ftA [f=7][b=8][yy=66][chb=8][xx=66][8ch] bf16   (31.22 MB)
//   wt2 [s=63][e=4][hh=2][n=128][8ch]      bf16   (2.06 MB), s = f*9 + j
#define FT3_SHORTS 15611904u   // 56 planes x 66*8*66*8
#define PLANE_FB   278784u     // shorts per (f,b) plane

typedef __attribute__((address_space(3))) unsigned int lds_u32_t;
typedef __attribute__((address_space(1))) const unsigned int g_u32_t;

__device__ __forceinline__ unsigned short f2bf(float x) {
    union { float f; unsigned u; } v; v.f = x;
    unsigned r = v.u + 0x7FFFu + ((v.u >> 16) & 1u);   // RNE bf16
    return (unsigned short)(r >> 16);
}

// 7 features: [silu, 6 spline bases] (the old 8th slot was always 0)
__device__ __forceinline__ void feat7(float p, unsigned short* uf) {
    float e   = __expf(-p);
    float sig = 1.f / (1.f + e);
    uf[0] = f2bf(p * sig);
    float u  = p * 1.5f + 4.5f;
    float fj = floorf(u);
    int   j0 = (int)fj;
    float t  = u - fj;
    bool  inr = (u >= 0.f) && (u < 9.f);
    float t2 = t * t, t3 = t2 * t;
    const float c16 = 1.f / 6.f;
    float r0 = t3 * c16;
    float r1 = (-3.f * t3 + 3.f * t2 + 3.f * t + 1.f) * c16;
    float r2 = (3.f * t3 - 6.f * t2 + 4.f) * c16;
    float s1 = 1.f - t;
    float r3 = s1 * s1 * s1 * c16;
#pragma unroll
    for (int g = 0; g < 6; ++g) {
        int r = j0 - g;
        float v = (r == 0) ? r0 : ((r == 1) ? r1 : ((r == 2) ? r2 : ((r == 3) ? r3 : 0.f)));
        uf[1 + g] = f2bf(inr ? v : 0.f);
    }
}

// ---- Prep v3: grid 1024 x 256, no LDS/sync. Block = (line 0..511, half 0..1).
// Thread (xx, g): chb = half*4+g -> 8 channels of one pixel: read 32 B of x,
// 8x feat7, transpose-pack per f -> 7 x 16B stores (each wave: 1 KB bursts).
// Halo: 116480 16B pad cells spread 114/block. B: 73728 (o,i) pairs, 72/block.
__global__ __launch_bounds__(256)
void prep_all(const float* __restrict__ x,
              const float* __restrict__ bw, const float* __restrict__ sw,
              unsigned short* __restrict__ ft, unsigned short* __restrict__ wt) {
    const int blk  = blockIdx.x;         // 0..1023
    const int tid  = threadIdx.x;
    const int line = blk >> 1;           // 0..511
    const int half = blk & 1;

    // (1) B prep: value(f, o, i=(c,j)) -> wt2[s=f*9+j][e=c/16][hh=(c/8)&1][o][c&7]
    if (tid < 72) {
        int idx = blk * 72 + tid;        // 1024*72 = 73728 = 576*128
        int o = idx / 576;
        int i = idx - o * 576;
        int c = i / 9;
        int j = i - c * 9;
        int e = c >> 4, hh = (c >> 3) & 1, slot = c & 7;
        size_t base = (size_t)(e * 2 + hh) * 1024 + o * 8 + slot;
        const float* s6 = sw + (size_t)(o * 576 + i) * 6;
        wt[(size_t)j * 8192 + base] = f2bf(bw[o * 576 + i]);
#pragma unroll
        for (int f = 1; f < 7; ++f)
            wt[(size_t)(f * 9 + j) * 8192 + base] = f2bf(s6[f - 1]);
    }

    // (2) halo: idx = ((f*8+b)*8+chb)*260 + cell, 16B pad per cell
    {
        int t = blk * 114 + tid;
        if (tid < 114 && t < 116480) {
            int cell = t % 260;
            int rem  = t / 260;          // 0..447 = f*64 + b*8 + chb
            int chb_ = rem & 7, b_ = (rem >> 3) & 7, f_ = rem >> 6;
            const unsigned short padv[7] =
                { 0, 0, 0x3CAB, 0x3EF5, 0x3EF5, 0x3CAB, 0 };
            unsigned short pv = padv[f_];
            int yy, xx;
            if (cell < 66)       { yy = 0;          xx = cell; }
            else if (cell < 132) { yy = 65;         xx = cell - 66; }
            else if (cell < 196) { yy = cell - 131; xx = 0; }
            else                 { yy = cell - 195; xx = 65; }
            union { unsigned short u[8]; uint4 v; } pk;
#pragma unroll
            for (int k = 0; k < 8; ++k) pk.u[k] = pv;
            size_t off = ((((size_t)(f_ * 8 + b_) * 66 + yy) * 8 + chb_) * 66 + xx) * 8;
            *(uint4*)(ft + off) = pk.v;
        }
    }

    // (3) features: 8 channels (chb) of pixel (line, xx)
    const int xx  = tid & 63;
    const int g   = tid >> 6;            // 0..3
    const int chb = half * 4 + g;        // 0..7
    const int b   = line >> 6, y = line & 63;

    float4 v0 = *(const float4*)(x + (size_t)line * 4096 + xx * 64 + chb * 8);
    float4 v1 = *(const float4*)(x + (size_t)line * 4096 + xx * 64 + chb * 8 + 4);

    unsigned short uf[8][7];
    feat7(v0.x, uf[0]); feat7(v0.y, uf[1]); feat7(v0.z, uf[2]); feat7(v0.w, uf[3]);
    feat7(v1.x, uf[4]); feat7(v1.y, uf[5]); feat7(v1.z, uf[6]); feat7(v1.w, uf[7]);

#pragma unroll
    for (int f = 0; f < 7; ++f) {
        union { unsigned short u[8]; uint4 w; } pk;
#pragma unroll
        for (int ch = 0; ch < 8; ++ch) pk.u[ch] = uf[ch][f];
        size_t off = ((((size_t)(f * 8 + b) * 66 + (y + 1)) * 8 + chb) * 66 + (xx + 1)) * 8;
        *(uint4*)(ft + off) = pk.w;
    }
}

// ---- Main GEMM: R6 structure with dead-K removed: 63 slabs (one per (f,j)),
// K = 4032 real instead of 4608 padded (-12.5% MFMA, staged bytes, ds_reads).
// tile 64m(1 line) x 128n, grid 512, block 512 (8 waves), 2 blocks/CU, XCD
// swizzle. Slab staging: B 16 KB contiguous + A 8 x 1KB rows (one (f,j) decode
// per STAGE, no per-chunk division). LDS layouts and COMPUTE identical to R6.
#define BUF_SHORTS 12288

#define STAGE(sl, q_)                                                                 \
    {                                                                                 \
        unsigned short* bufq = Bufs + (q_) * BUF_SHORTS;                              \
        int f_  = ((sl) * 7282) >> 16;                                                \
        int j_  = (sl) - f_ * 9;                                                      \
        int kh_ = (j_ * 11) >> 5;                                                     \
        int kw_ = j_ - kh_ * 3;                                                       \
        const unsigned short* bsrc = wt + (size_t)(sl) * 8192;                        \
        const unsigned short* abase = ft +                                            \
            ((((size_t)(f_ * 8 + b) * 66 + (y + kh_)) * 8) * 66 + kw_) * 8;           \
        _Pragma("unroll")                                                             \
        for (int t = 0; t < 3; ++t) {                                                 \
            int u = wave * 3 + t;            /* 0..23: u<16 = B, u>=16 = A */         \
            if (u < 16) {                                                             \
                int boff = u * 512 + lane * 8;                                        \
                __builtin_amdgcn_global_load_lds((g_u32_t*)(bsrc + boff),             \
                                                 (lds_u32_t*)(bufq + boff), 16, 0, 0);\
            } else {                                                                  \
                int chb = u - 16;            /* 0..7 */                               \
                const unsigned short* asrc = abase + chb * 528 + lane * 8;            \
                unsigned short* adst = bufq + 8192 + chb * 512 + lane * 8;            \
                __builtin_amdgcn_global_load_lds((g_u32_t*)asrc, (lds_u32_t*)adst,    \
                                                 16, 0, 0);                           \
            }                                                                         \
        }                                                                             \
    }

#define COMPUTE(q_)                                                                   \
    {                                                                                 \
        const unsigned short* bufr = Bufs + (q_) * BUF_SHORTS;                        \
        const unsigned short* Ab = bufr + 8192 + iloc * 512;                          \
        const unsigned short* Bb = bufr + iloc * 1024 + nh * 512;                     \
        short8 a0 = *(const short8*)(Ab + l32 * 8);                                   \
        short8 a1 = *(const short8*)(Ab + (32 + l32) * 8);                            \
        short8 b0 = *(const short8*)(Bb + l32 * 8);                                   \
        short8 b1 = *(const short8*)(Bb + 256 + l32 * 8);                             \
        acc00 = __builtin_amdgcn_mfma_f32_32x32x16_bf16(a0, b0, acc00, 0, 0, 0);      \
        acc01 = __builtin_amdgcn_mfma_f32_32x32x16_bf16(a0, b1, acc01, 0, 0, 0);      \
        acc10 = __builtin_amdgcn_mfma_f32_32x32x16_bf16(a1, b0, acc10, 0, 0, 0);      \
        acc11 = __builtin_amdgcn_mfma_f32_32x32x16_bf16(a1, b1, acc11, 0, 0, 0);      \
    }

#define PHASE(q_, n_, stagesl, dostage_)                                              \
    {                                                                                 \
        asm volatile("s_waitcnt vmcnt(" #n_ ")" ::: "memory");                        \
        __builtin_amdgcn_s_barrier();                                                 \
        asm volatile("" ::: "memory");                                                \
        __builtin_amdgcn_s_setprio(1);                                                \
        COMPUTE(q_)                                                                   \
        __builtin_amdgcn_s_setprio(0);                                                \
        asm volatile("" ::: "memory");                                                \
        __builtin_amdgcn_s_barrier();                                                 \
        asm volatile("" ::: "memory");                                                \
        if (dostage_) STAGE(stagesl, q_);                                             \
    }

// Epilogue reduce helpers: conflict-free float4 layout (lane-stride 16 B).
#define DUMPA(base_, A_)                                                              \
    {   float4* s4 = (float4*)(red + (base_));                                        \
        _Pragma("unroll")                                                             \
        for (int c = 0; c < 4; ++c)                                                   \
            s4[c * 64 + lane] = make_float4(A_[4*c], A_[4*c+1], A_[4*c+2], A_[4*c+3]); }
#define ADDA(base_, A_)                                                               \
    {   const float4* s4 = (const float4*)(red + (base_));                            \
        _Pragma("unroll")                                                             \
        for (int c = 0; c < 4; ++c) {                                                 \
            float4 rv = s4[c * 64 + lane];                                            \
            A_[4*c] += rv.x; A_[4*c+1] += rv.y; A_[4*c+2] += rv.z; A_[4*c+3] += rv.w; } }

__global__ __launch_bounds__(512, 4)
void convkan_gemm(const unsigned short* __restrict__ ft,
                  const unsigned short* __restrict__ wt,
                  const float* __restrict__ bias,
                  float* __restrict__ out) {
    extern __shared__ unsigned short Bufs[];     // 3 x 12288 shorts = 72 KB

    const int tid  = threadIdx.x;
    const int blk  = blockIdx.x;                 // 0..511
    const int mb   = ((blk & 7) << 6) | (blk >> 3);  // XCD swizzle: XCD owns image
    const int lane = tid & 63;
    const int wave = tid >> 6;                   // 0..7
    const int kq   = wave >> 1;                  // K-quarter 0..3 (16 channels)
    const int nh   = wave & 1;                   // n-half (64 ch)
    const int l32  = lane & 31;
    const int h    = lane >> 5;                  // k-half within MFMA K16
    const int iloc = (kq << 1) + h;              // chb / B-slice this half consumes

    const int b = mb >> 6;                       // image 0..7
    const int y = mb & 63;                       // line 0..63

    f32x16 acc00, acc01, acc10, acc11;
#pragma unroll
    for (int e = 0; e < 16; ++e) { acc00[e] = 0.f; acc01[e] = 0.f; acc10[e] = 0.f; acc11[e] = 0.f; }

    // prologue: fill the 3-deep pipeline (slabs 0,1,2)
    STAGE(0, 0);
    STAGE(1, 1);
    STAGE(2, 2);

    // steady state: phases 0..59 stage slabs 3..62
    for (int it3 = 0; it3 < 20; ++it3) {
        const int it = it3 * 3;
        PHASE(0, 6, it + 3, true)
        PHASE(1, 6, it + 4, true)
        PHASE(2, 6, it + 5, true)
    }
    // tail: phases 60, 61, 62 — drain pipeline
    PHASE(0, 6, 0, false)
    PHASE(1, 3, 0, false)
    PHASE(2, 0, 0, false)

    // ---- K-partial reduction across kq (3 rounds via LDS), then store ----
    __syncthreads();
    float* red = (float*)Bufs;

    if (kq >= 2) { DUMPA(((nh << 1) + (kq - 2)) * 2048,        acc00);
                   DUMPA(((nh << 1) + (kq - 2)) * 2048 + 1024, acc01); }
    __syncthreads();
    if (kq < 2)  { ADDA(((nh << 1) + kq) * 2048,        acc00);
                   ADDA(((nh << 1) + kq) * 2048 + 1024, acc01); }
    __syncthreads();
    if (kq >= 2) { DUMPA(((nh << 1) + (kq - 2)) * 2048,        acc10);
                   DUMPA(((nh << 1) + (kq - 2)) * 2048 + 1024, acc11); }
    __syncthreads();
    if (kq < 2)  { ADDA(((nh << 1) + kq) * 2048,        acc10);
                   ADDA(((nh << 1) + kq) * 2048 + 1024, acc11); }
    __syncthreads();
    if (kq == 1) { DUMPA(nh * 4096,        acc00); DUMPA(nh * 4096 + 1024, acc01);
                   DUMPA(nh * 4096 + 2048, acc10); DUMPA(nh * 4096 + 3072, acc11); }
    __syncthreads();
    if (kq == 0) {
        ADDA(nh * 4096,        acc00); ADDA(nh * 4096 + 1024, acc01);
        ADDA(nh * 4096 + 2048, acc10); ADDA(nh * 4096 + 3072, acc11);

        const int ncol = nh * 64 + l32;
        const float bv0 = bias[ncol];
        const float bv1 = bias[ncol + 32];
        const int prow = mb * 64;                // output pixel-row base
#pragma unroll
        for (int r = 0; r < 16; ++r) {
            int mrow = (r & 3) + ((r >> 2) << 3) + 4 * h;
            float* p = out + (size_t)(prow + mrow) * 128 + ncol;
            p[0]  = acc00[r] + bv0;
            p[32] = acc01[r] + bv1;
            float* p2 = out + (size_t)(prow + 32 + mrow) * 128 + ncol;
            p2[0]  = acc10[r] + bv0;
            p2[32] = acc11[r] + bv1;
        }
    }
}

extern "C" void kernel_launch(void* const* d_in, const int* in_sizes, int n_in,
                              void* d_out, int out_size, void* d_ws, size_t ws_size,
                              hipStream_t stream) {
    (void)in_sizes; (void)n_in; (void)ws_size; (void)out_size;
    const float* x        = (const float*)d_in[0];
    const float* base_w   = (const float*)d_in[1];
    const float* spline_w = (const float*)d_in[2];
    const float* bias     = (const float*)d_in[3];
    float* out = (float*)d_out;

    unsigned short* ft = (unsigned short*)d_ws;      // 31.22 MB feature planes
    unsigned short* wt = ft + FT3_SHORTS;            // 2.06 MB tiled B (fj-major)

    hipLaunchKernelGGL(prep_all, dim3(1024), dim3(256), 0, stream,
                       x, base_w, spline_w, ft, wt);

    const int shmem = 3 * BUF_SHORTS * 2;            // 72 KB -> 2 blocks/CU
    (void)hipFuncSetAttribute((const void*)convkan_gemm,
                              hipFuncAttributeMaxDynamicSharedMemorySize, shmem);
    hipLaunchKernelGGL(convkan_gemm, dim3(512), dim3(512), shmem, stream,
                       ft, wt, bias, out);
}